// Round 4
// baseline (949.800 us; speedup 1.0000x reference)
//
#include <hip/hip_runtime.h>

#define EDGES   800000
#define IN_F    64
#define HID     128
#define TPB     512                 // 8 waves per WG
#define EPW     32                  // edges per wave = one 32-col MFMA tile
#define EPB     256                 // edges per WG (8 waves * 32)
#define NBLK    (EDGES / EPB)       // 3125 edge blocks
#define GRID    256                 // persistent: 1 WG/CU

// LDS layout: [w1 16KB | w2 32KB | w3 32KB | b1 | b2 | b3 | w4], f16 weights XOR-swizzled.
#define W1_OFF  0
#define W2_OFF  16384
#define W3_OFF  49152
#define B1_OFF  81920
#define B2_OFF  82432
#define B3_OFF  82944
#define W4_OFF  83456
#define LDSB    83968

typedef _Float16 half8  __attribute__((ext_vector_type(8)));
typedef __fp16   fp16x2 __attribute__((ext_vector_type(2)));
typedef float    f32x16 __attribute__((ext_vector_type(16)));
typedef unsigned u32;
typedef u32      u32x2  __attribute__((ext_vector_type(2)));
typedef u32      u32x4  __attribute__((ext_vector_type(4)));

__device__ __forceinline__ float fast_tanh(float x) {
    // tanh(x) = 1 - 2/(e^{2x}+1); preacts bounded, no overflow.
    float e = __builtin_amdgcn_exp2f(2.8853900817779268f * x);
    return 1.0f - 2.0f * __builtin_amdgcn_rcpf(e + 1.0f);
}
__device__ __forceinline__ float fast_sigmoid(float x) {
    return __builtin_amdgcn_rcpf(1.0f + __builtin_amdgcn_exp2f(-1.4426950408889634f * x));
}
__device__ __forceinline__ u32 pk2(float a, float b) {
    fp16x2 p = __builtin_amdgcn_cvt_pkrtz(a, b);
    return __builtin_bit_cast(u32, p);
}
__device__ __forceinline__ half8 cvt8(float4 a, float4 b) {
    half8 h;
    h[0]=(_Float16)a.x; h[1]=(_Float16)a.y; h[2]=(_Float16)a.z; h[3]=(_Float16)a.w;
    h[4]=(_Float16)b.x; h[5]=(_Float16)b.y; h[6]=(_Float16)b.z; h[7]=(_Float16)b.w;
    return h;
}

// ---- all helpers take/return fragments BY VALUE: pure SSA, no allocas ----

struct HPair { half8 lo, hi; };

// tanh + pack 16 accs -> 8 dwords d[M][k] (rows 8M+4hi+{2k,2k+1}), then
// permlane32_swap pairs -> next layer B-frags (verified layout, rounds 1-3).
__device__ __forceinline__ HPair pack_swap(f32x16 acc) {
    u32 d00 = pk2(fast_tanh(acc[0]),  fast_tanh(acc[1]));
    u32 d01 = pk2(fast_tanh(acc[2]),  fast_tanh(acc[3]));
    u32 d10 = pk2(fast_tanh(acc[4]),  fast_tanh(acc[5]));
    u32 d11 = pk2(fast_tanh(acc[6]),  fast_tanh(acc[7]));
    u32 d20 = pk2(fast_tanh(acc[8]),  fast_tanh(acc[9]));
    u32 d21 = pk2(fast_tanh(acc[10]), fast_tanh(acc[11]));
    u32 d30 = pk2(fast_tanh(acc[12]), fast_tanh(acc[13]));
    u32 d31 = pk2(fast_tanh(acc[14]), fast_tanh(acc[15]));
    u32x2 r0 = __builtin_amdgcn_permlane32_swap(d00, d10, false, false);
    u32x2 r1 = __builtin_amdgcn_permlane32_swap(d01, d11, false, false);
    u32x2 r2 = __builtin_amdgcn_permlane32_swap(d20, d30, false, false);
    u32x2 r3 = __builtin_amdgcn_permlane32_swap(d21, d31, false, false);
    HPair o;
    o.lo = __builtin_bit_cast(half8, (u32x4){r0[0], r1[0], r0[1], r1[1]});
    o.hi = __builtin_bit_cast(half8, (u32x4){r2[0], r3[0], r2[1], r3[1]});
    return o;
}

// bias-init accumulator from LDS (f32, broadcast reads)
__device__ __forceinline__ f32x16 bias_init(const char* p) {
    float4 v0 = *(const float4*)(p);
    float4 v1 = *(const float4*)(p + 32);
    float4 v2 = *(const float4*)(p + 64);
    float4 v3 = *(const float4*)(p + 96);
    f32x16 a;
    a[0]=v0.x;  a[1]=v0.y;  a[2]=v0.z;  a[3]=v0.w;
    a[4]=v1.x;  a[5]=v1.y;  a[6]=v1.z;  a[7]=v1.w;
    a[8]=v2.x;  a[9]=v2.y;  a[10]=v2.z; a[11]=v2.w;
    a[12]=v3.x; a[13]=v3.y; a[14]=v3.z; a[15]=v3.w;
    return a;
}

// A-frag swizzled reads: offset (s<<5) ^ swb with compile-time s
// (== original sw[] table: summed bits are disjoint, XOR is bitwise).
__device__ __forceinline__ f32x16 mm4(const char* B, int rowb, u32 swb,
                                      half8 b0, half8 b1, half8 b2, half8 b3,
                                      f32x16 acc) {
    const char* p = B + rowb;
#define MMSTEP(S, BF) acc = __builtin_amdgcn_mfma_f32_32x32x16_f16( \
        *(const half8*)(p + ((u32)(S << 5) ^ swb)), BF, acc, 0, 0, 0)
    MMSTEP(0, b0); MMSTEP(1, b1); MMSTEP(2, b2); MMSTEP(3, b3);
    return acc;
}
__device__ __forceinline__ f32x16 mm8(const char* B, int rowb, u32 swb,
                                      half8 b0, half8 b1, half8 b2, half8 b3,
                                      half8 b4, half8 b5, half8 b6, half8 b7,
                                      f32x16 acc) {
    const char* p = B + rowb;
    MMSTEP(0, b0); MMSTEP(1, b1); MMSTEP(2, b2); MMSTEP(3, b3);
    MMSTEP(4, b4); MMSTEP(5, b5); MMSTEP(6, b6); MMSTEP(7, b7);
#undef MMSTEP
    return acc;
}

// Occupancy: 80KiB+ LDS -> 1 WG/CU = 2 waves/SIMD regardless of regs, so give
// the allocator the matching 256-VGPR budget explicitly (waves_per_eu 2,2).
// History: __launch_bounds__ (512,4)/(512,2)/(512,1) gave 64/128/128-VGPR caps
// with persistent scratch traffic -> arrays were allocas, not register state.
__global__ __attribute__((amdgpu_flat_work_group_size(TPB, TPB)))
__attribute__((amdgpu_waves_per_eu(2, 2)))
void gnn_mlp(const float* __restrict__ ea,
             const float* __restrict__ W1, const float* __restrict__ b1,
             const float* __restrict__ W2, const float* __restrict__ b2,
             const float* __restrict__ W3, const float* __restrict__ b3,
             const float* __restrict__ W4, const float* __restrict__ b4,
             float* __restrict__ out) {
    __shared__ __align__(16) char LW[LDSB];

    const int tid  = threadIdx.x;
    const int lane = tid & 63;
    const int wv   = tid >> 6;          // wave 0..7
    const int col  = lane & 31;         // edge column of the 32x32 tile
    const int hi   = lane >> 5;         // k-half selector

    // ---- stage weights: f32 -> f16, XOR-swizzled, once per WG ----
    #pragma unroll
    for (int i = 0; i < 10; ++i) {
        const int g   = i * TPB + tid;  // 16B granule id, 5120 total
        const int off = g << 4;
        const float* src; int phys;
        if (i < 2) {                    // w1: rows of 128 B
            int row = off >> 7;
            phys = W1_OFF + (off ^ ((row & 7) << 4));
            src  = W1 + (off >> 1);
        } else if (i < 6) {             // w2: rows of 256 B
            int rel = off - W2_OFF, row = rel >> 8;
            phys = W2_OFF + (rel ^ ((row & 15) << 4));
            src  = W2 + (rel >> 1);
        } else {                        // w3
            int rel = off - W3_OFF, row = rel >> 8;
            phys = W3_OFF + (rel ^ ((row & 15) << 4));
            src  = W3 + (rel >> 1);
        }
        float4 a = *(const float4*)(src);
        float4 b = *(const float4*)(src + 4);
        *(half8*)(LW + phys) = cvt8(a, b);
    }
    // ---- stage biases + W4 (f32) ----
    if (tid < 128)      *(float*)(LW + B1_OFF + tid * 4)         = b1[tid];
    else if (tid < 256) *(float*)(LW + B2_OFF + (tid - 128) * 4) = b2[tid - 128];
    else if (tid < 384) *(float*)(LW + B3_OFF + (tid - 256) * 4) = b3[tid - 256];
    else                *(float*)(LW + W4_OFF + (tid - 384) * 4) = W4[tid - 384];
    __syncthreads();   // only barrier in the kernel

    const u32 swb1 = (u32)((hi << 4) ^ ((col & 7) << 4));
    const u32 swb2 = (u32)((hi << 4) ^ ((col & 15) << 4));
    const int hi16 = hi << 4;
    const char* LW1 = LW + W1_OFF;
    const char* LW2 = LW + W2_OFF;
    const char* LW3 = LW + W3_OFF;
    const char* LB1 = LW + B1_OFF + hi16;
    const char* LB2 = LW + B2_OFF + hi16;
    const char* LB3 = LW + B3_OFF + hi16;
    const char* LV4 = LW + W4_OFF + hi16;
    const float bb  = b4[0];
    const int colr1 = col << 7;
    const int colr2 = col << 8;

    // ---- software prefetch: named float4 regs, 1 block deep ----
    {
        const float* ep = ea + ((long)blockIdx.x * EPB + wv * EPW + col) * IN_F + hi * 8;
        float4 r0 = *(const float4*)(ep);      float4 r1 = *(const float4*)(ep + 4);
        float4 r2 = *(const float4*)(ep + 16); float4 r3 = *(const float4*)(ep + 20);
        float4 r4 = *(const float4*)(ep + 32); float4 r5 = *(const float4*)(ep + 36);
        float4 r6 = *(const float4*)(ep + 48); float4 r7 = *(const float4*)(ep + 52);

        for (int blk = blockIdx.x; blk < NBLK; blk += GRID) {
            const long ebase = (long)blk * EPB + wv * EPW;

            half8 f1_0 = cvt8(r0, r1), f1_1 = cvt8(r2, r3),
                  f1_2 = cvt8(r4, r5), f1_3 = cvt8(r6, r7);

            if (blk + GRID < NBLK) {
                const float* np = ea + ((long)(blk + GRID) * EPB + wv * EPW + col) * IN_F + hi * 8;
                r0 = *(const float4*)(np);      r1 = *(const float4*)(np + 4);
                r2 = *(const float4*)(np + 16); r3 = *(const float4*)(np + 20);
                r4 = *(const float4*)(np + 32); r5 = *(const float4*)(np + 36);
                r6 = *(const float4*)(np + 48); r7 = *(const float4*)(np + 52);
            }

            // ---- layer 1: 64 -> 128 (4 tiles x 4 k-steps) ----
            HPair t0, t1, t2, t3;
            { f32x16 a = bias_init(LB1);       a = mm4(LW1, (0<<12) + colr1, swb1, f1_0, f1_1, f1_2, f1_3, a); t0 = pack_swap(a); }
            { f32x16 a = bias_init(LB1 + 128); a = mm4(LW1, (1<<12) + colr1, swb1, f1_0, f1_1, f1_2, f1_3, a); t1 = pack_swap(a); }
            { f32x16 a = bias_init(LB1 + 256); a = mm4(LW1, (2<<12) + colr1, swb1, f1_0, f1_1, f1_2, f1_3, a); t2 = pack_swap(a); }
            { f32x16 a = bias_init(LB1 + 384); a = mm4(LW1, (3<<12) + colr1, swb1, f1_0, f1_1, f1_2, f1_3, a); t3 = pack_swap(a); }
            half8 f2_0 = t0.lo, f2_1 = t0.hi, f2_2 = t1.lo, f2_3 = t1.hi,
                  f2_4 = t2.lo, f2_5 = t2.hi, f2_6 = t3.lo, f2_7 = t3.hi;

            // ---- layer 2: 128 -> 128 (4 tiles x 8 k-steps) ----
            { f32x16 a = bias_init(LB2);       a = mm8(LW2, (0<<13) + colr2, swb2, f2_0, f2_1, f2_2, f2_3, f2_4, f2_5, f2_6, f2_7, a); t0 = pack_swap(a); }
            { f32x16 a = bias_init(LB2 + 128); a = mm8(LW2, (1<<13) + colr2, swb2, f2_0, f2_1, f2_2, f2_3, f2_4, f2_5, f2_6, f2_7, a); t1 = pack_swap(a); }
            { f32x16 a = bias_init(LB2 + 256); a = mm8(LW2, (2<<13) + colr2, swb2, f2_0, f2_1, f2_2, f2_3, f2_4, f2_5, f2_6, f2_7, a); t2 = pack_swap(a); }
            { f32x16 a = bias_init(LB2 + 384); a = mm8(LW2, (3<<13) + colr2, swb2, f2_0, f2_1, f2_2, f2_3, f2_4, f2_5, f2_6, f2_7, a); t3 = pack_swap(a); }
            half8 f3_0 = t0.lo, f3_1 = t0.hi, f3_2 = t1.lo, f3_3 = t1.hi,
                  f3_4 = t2.lo, f3_5 = t2.hi, f3_6 = t3.lo, f3_7 = t3.hi;

            // ---- layer 3 + fused layer-4 dot ----
            float p = 0.0f;
#define L3TILE(IT) { \
            f32x16 a = bias_init(LB3 + (IT)*128); \
            a = mm8(LW3, ((IT)<<13) + colr2, swb2, f3_0, f3_1, f3_2, f3_3, f3_4, f3_5, f3_6, f3_7, a); \
            float4 w0 = *(const float4*)(LV4 + (IT)*128); \
            float4 w1 = *(const float4*)(LV4 + (IT)*128 + 32); \
            float4 w2 = *(const float4*)(LV4 + (IT)*128 + 64); \
            float4 w3 = *(const float4*)(LV4 + (IT)*128 + 96); \
            p += fast_tanh(a[0])*w0.x  + fast_tanh(a[1])*w0.y  + fast_tanh(a[2])*w0.z  + fast_tanh(a[3])*w0.w \
               + fast_tanh(a[4])*w1.x  + fast_tanh(a[5])*w1.y  + fast_tanh(a[6])*w1.z  + fast_tanh(a[7])*w1.w \
               + fast_tanh(a[8])*w2.x  + fast_tanh(a[9])*w2.y  + fast_tanh(a[10])*w2.z + fast_tanh(a[11])*w2.w \
               + fast_tanh(a[12])*w3.x + fast_tanh(a[13])*w3.y + fast_tanh(a[14])*w3.z + fast_tanh(a[15])*w3.w; }
            L3TILE(0); L3TILE(1); L3TILE(2); L3TILE(3);
#undef L3TILE

            // full h-sum for edge `col` lives in lanes col and col+32
            p += __shfl_xor(p, 32, 64);
            if (lane < 32) out[ebase + col] = fast_sigmoid(p + bb);
        }
    }
}

extern "C" void kernel_launch(void* const* d_in, const int* in_sizes, int n_in,
                              void* d_out, int out_size, void* d_ws, size_t ws_size,
                              hipStream_t stream) {
    // setup_inputs order: x, edge_index, edge_attr, W1,b1, W2,b2, W3,b3, W4,b4
    const float* ea = (const float*)d_in[2];
    const float* W1 = (const float*)d_in[3];
    const float* b1 = (const float*)d_in[4];
    const float* W2 = (const float*)d_in[5];
    const float* b2 = (const float*)d_in[6];
    const float* W3 = (const float*)d_in[7];
    const float* b3 = (const float*)d_in[8];
    const float* W4 = (const float*)d_in[9];
    const float* b4 = (const float*)d_in[10];
    float* out = (float*)d_out;

    hipLaunchKernelGGL(gnn_mlp, dim3(GRID), dim3(TPB), 0, stream,
                       ea, W1, b1, W2, b2, W3, b3, W4, b4, out);
}

// Round 6
// 350.313 us; speedup vs baseline: 2.7113x; 2.7113x over previous
//
#include <hip/hip_runtime.h>

#define EDGES   800000
#define IN_F    64
#define HID     128
#define TPB     512                 // 8 waves per WG
#define EPW     32                  // edges per wave = one 32-col MFMA tile
#define EPB     256                 // edges per WG (8 waves * 32)
#define NBLK    (EDGES / EPB)       // 3125 edge blocks
#define GRID    256                 // persistent: 1 WG/CU

// LDS: [w1 16K | w2 32K | w3 32K | b1 | b2 | b3 | w4 | H: 8 waves x 8K]
// f16 weights XOR-swizzled; H = per-wave activation staging, XOR-swizzled.
#define W1_OFF  0
#define W2_OFF  16384
#define W3_OFF  49152
#define B1_OFF  81920
#define B2_OFF  82432
#define B3_OFF  82944
#define W4_OFF  83456
#define H_OFF   83968
#define LDSB    (H_OFF + 8 * 8192)  // 149504 <= 160 KiB

typedef _Float16 half8  __attribute__((ext_vector_type(8)));
typedef __fp16   fp16x2 __attribute__((ext_vector_type(2)));
typedef float    f32x16 __attribute__((ext_vector_type(16)));
typedef unsigned u32;
typedef u32      u32x2  __attribute__((ext_vector_type(2)));

__device__ __forceinline__ float fast_tanh(float x) {
    // tanh(x) = 1 - 2/(e^{2x}+1); preacts bounded, no overflow.
    float e = __builtin_amdgcn_exp2f(2.8853900817779268f * x);
    return 1.0f - 2.0f * __builtin_amdgcn_rcpf(e + 1.0f);
}
__device__ __forceinline__ float fast_sigmoid(float x) {
    return __builtin_amdgcn_rcpf(1.0f + __builtin_amdgcn_exp2f(-1.4426950408889634f * x));
}
__device__ __forceinline__ u32 pk2(float a, float b) {
    fp16x2 p = __builtin_amdgcn_cvt_pkrtz(a, b);
    return __builtin_bit_cast(u32, p);
}
__device__ __forceinline__ half8 cvt8(float4 a, float4 b) {
    half8 h;
    h[0]=(_Float16)a.x; h[1]=(_Float16)a.y; h[2]=(_Float16)a.z; h[3]=(_Float16)a.w;
    h[4]=(_Float16)b.x; h[5]=(_Float16)b.y; h[6]=(_Float16)b.z; h[7]=(_Float16)b.w;
    return h;
}

// bias-init accumulator from LDS (f32 broadcast reads; layout round-4-verified)
__device__ __forceinline__ f32x16 bias_init(const char* p) {
    float4 v0 = *(const float4*)(p);
    float4 v1 = *(const float4*)(p + 32);
    float4 v2 = *(const float4*)(p + 64);
    float4 v3 = *(const float4*)(p + 96);
    f32x16 a;
    a[0]=v0.x;  a[1]=v0.y;  a[2]=v0.z;  a[3]=v0.w;
    a[4]=v1.x;  a[5]=v1.y;  a[6]=v1.z;  a[7]=v1.w;
    a[8]=v2.x;  a[9]=v2.y;  a[10]=v2.z; a[11]=v2.w;
    a[12]=v3.x; a[13]=v3.y; a[14]=v3.z; a[15]=v3.w;
    return a;
}

// A-frag (weight) swizzled reads, layout verified rounds 1-4.
__device__ __forceinline__ f32x16 mm4(const char* B, int rowb, u32 swb,
                                      half8 b0, half8 b1, half8 b2, half8 b3,
                                      f32x16 acc) {
    const char* p = B + rowb;
#define MMSTEP(S, BF) acc = __builtin_amdgcn_mfma_f32_32x32x16_f16( \
        *(const half8*)(p + ((u32)(S << 5) ^ swb)), BF, acc, 0, 0, 0)
    MMSTEP(0, b0); MMSTEP(1, b1); MMSTEP(2, b2); MMSTEP(3, b3);
    return acc;
}
__device__ __forceinline__ f32x16 mm8(const char* B, int rowb, u32 swb,
                                      half8 b0, half8 b1, half8 b2, half8 b3,
                                      half8 b4, half8 b5, half8 b6, half8 b7,
                                      f32x16 acc) {
    const char* p = B + rowb;
    MMSTEP(0, b0); MMSTEP(1, b1); MMSTEP(2, b2); MMSTEP(3, b3);
    MMSTEP(4, b4); MMSTEP(5, b5); MMSTEP(6, b6); MMSTEP(7, b7);
#undef MMSTEP
    return acc;
}

// D layout (verified): lane(col,hi) reg r of group M holds O[h'=32it+8M+4hi+r][col],
// r=0..3 consecutive -> two pk2 dwords = 4 consecutive h' -> one ds_write_b64.
// H row = edge col (256 B), swizzle: byte ^ ((col&15)<<4) (bits 4-7 only, keeps
// 8B/16B alignment). Write phys(L) = ((L&0xF0)^wsw)|(L&0x0F) == read phys(L):
// write XORs (itb+16M) = L&0xF0, adds hi8+delta < 16; read XORs Lr (low nibble
// 0), adds delta < 16. Consistent; conflict-free b128 reads.
__device__ __forceinline__ void store_tile(char* HB, u32 wsw, int itb, int hi8, f32x16 acc) {
    #pragma unroll
    for (int M = 0; M < 4; ++M) {
        u32 a = pk2(fast_tanh(acc[4*M+0]), fast_tanh(acc[4*M+1]));
        u32 b = pk2(fast_tanh(acc[4*M+2]), fast_tanh(acc[4*M+3]));
        *(u32x2*)(HB + (((itb + 16*M) ^ (int)wsw) + hi8)) = (u32x2){a, b};
    }
}
__device__ __forceinline__ half8 hread(const char* HB, u32 wsw, int off) {
    return *(const half8*)(HB + (off ^ (int)wsw));
}

// Register-pressure design note (rounds 1-4 post-mortem): VGPR cap is pinned at
// 128 by the toolchain regardless of launch_bounds/waves_per_eu; holding both a
// layer's 8 input frags AND 8 output frags in regs (64 VGPRs) + acc + prefetch
// overflowed it -> persistent scratch traffic (216-561 MB writes). This version
// stages inter-layer activations through wave-private LDS: peak live ~90 VGPRs.
__global__ __launch_bounds__(TPB, 2)
void gnn_mlp(const float* __restrict__ ea,
             const float* __restrict__ W1, const float* __restrict__ b1,
             const float* __restrict__ W2, const float* __restrict__ b2,
             const float* __restrict__ W3, const float* __restrict__ b3,
             const float* __restrict__ W4, const float* __restrict__ b4,
             float* __restrict__ out) {
    __shared__ __align__(16) char LW[LDSB];

    const int tid  = threadIdx.x;
    const int lane = tid & 63;
    const int wv   = tid >> 6;          // wave 0..7
    const int col  = lane & 31;         // edge column of the 32x32 tile
    const int hi   = lane >> 5;         // k-half selector

    // ---- stage weights: f32 -> f16, XOR-swizzled, once per WG ----
    #pragma unroll
    for (int i = 0; i < 10; ++i) {
        const int g   = i * TPB + tid;  // 16B granule id, 5120 total
        const int off = g << 4;
        const float* src; int phys;
        if (i < 2) {                    // w1: rows of 128 B
            int row = off >> 7;
            phys = W1_OFF + (off ^ ((row & 7) << 4));
            src  = W1 + (off >> 1);
        } else if (i < 6) {             // w2: rows of 256 B
            int rel = off - W2_OFF, row = rel >> 8;
            phys = W2_OFF + (rel ^ ((row & 15) << 4));
            src  = W2 + (rel >> 1);
        } else {                        // w3
            int rel = off - W3_OFF, row = rel >> 8;
            phys = W3_OFF + (rel ^ ((row & 15) << 4));
            src  = W3 + (rel >> 1);
        }
        float4 a = *(const float4*)(src);
        float4 b = *(const float4*)(src + 4);
        *(half8*)(LW + phys) = cvt8(a, b);
    }
    // ---- stage biases + W4 (f32) ----
    if (tid < 128)      *(float*)(LW + B1_OFF + tid * 4)         = b1[tid];
    else if (tid < 256) *(float*)(LW + B2_OFF + (tid - 128) * 4) = b2[tid - 128];
    else if (tid < 384) *(float*)(LW + B3_OFF + (tid - 256) * 4) = b3[tid - 256];
    else                *(float*)(LW + W4_OFF + (tid - 384) * 4) = W4[tid - 384];
    __syncthreads();   // only barrier in the kernel

    const u32 swb1 = (u32)((hi << 4) ^ ((col & 7) << 4));   // weight swizzles
    const u32 swb2 = (u32)((hi << 4) ^ ((col & 15) << 4));
    const u32 wsw  = (u32)((col & 15) << 4);                // H swizzle
    const int hi16 = hi << 4;
    const int hi8  = hi << 3;
    const char* LW1 = LW + W1_OFF;
    const char* LW2 = LW + W2_OFF;
    const char* LW3 = LW + W3_OFF;
    const char* LB1 = LW + B1_OFF + hi16;
    const char* LB2 = LW + B2_OFF + hi16;
    const char* LB3 = LW + B3_OFF + hi16;
    const char* LV4 = LW + W4_OFF + hi16;
    char*       HB  = LW + H_OFF + wv * 8192 + col * 256;   // wave-private row
    const float bb  = b4[0];
    const int colr1 = col << 7;
    const int colr2 = col << 8;

    // ---- half-depth prefetch: next block's k in [0,32) (16 regs) ----
    {
        const float* ep = ea + ((long)blockIdx.x * EPB + wv * EPW + col) * IN_F + hi * 8;
        float4 s0 = *(const float4*)(ep);      float4 s1 = *(const float4*)(ep + 4);
        float4 s2 = *(const float4*)(ep + 16); float4 s3 = *(const float4*)(ep + 20);

        for (int blk = blockIdx.x; blk < NBLK; blk += GRID) {
            const long ebase = (long)blk * EPB + wv * EPW;
            const float* ec = ea + (ebase + col) * IN_F + hi * 8;

            // current block's second half k in [32,64)
            float4 c0 = *(const float4*)(ec + 32); float4 c1 = *(const float4*)(ec + 36);
            float4 c2 = *(const float4*)(ec + 48); float4 c3 = *(const float4*)(ec + 52);

            half8 f1_0 = cvt8(s0, s1), f1_1 = cvt8(s2, s3);

            if (blk + GRID < NBLK) {   // issue next block's first half now
                const float* en = ea + ((long)(blk + GRID) * EPB + wv * EPW + col) * IN_F + hi * 8;
                s0 = *(const float4*)(en);      s1 = *(const float4*)(en + 4);
                s2 = *(const float4*)(en + 16); s3 = *(const float4*)(en + 20);
            }
            half8 f1_2 = cvt8(c0, c1), f1_3 = cvt8(c2, c3);

            // ---- layer 1: 64 -> 128, results to H ----
            { f32x16 a = bias_init(LB1);       a = mm4(LW1, (0<<12)+colr1, swb1, f1_0,f1_1,f1_2,f1_3, a); store_tile(HB, wsw,   0, hi8, a); }
            { f32x16 a = bias_init(LB1 + 128); a = mm4(LW1, (1<<12)+colr1, swb1, f1_0,f1_1,f1_2,f1_3, a); store_tile(HB, wsw,  64, hi8, a); }
            { f32x16 a = bias_init(LB1 + 256); a = mm4(LW1, (2<<12)+colr1, swb1, f1_0,f1_1,f1_2,f1_3, a); store_tile(HB, wsw, 128, hi8, a); }
            { f32x16 a = bias_init(LB1 + 384); a = mm4(LW1, (3<<12)+colr1, swb1, f1_0,f1_1,f1_2,f1_3, a); store_tile(HB, wsw, 192, hi8, a); }

            // ---- layer 2: read frags, compute, write back to H ----
            {
                half8 g0 = hread(HB, wsw,   0 + hi16), g1 = hread(HB, wsw,  32 + hi16),
                      g2 = hread(HB, wsw,  64 + hi16), g3 = hread(HB, wsw,  96 + hi16),
                      g4 = hread(HB, wsw, 128 + hi16), g5 = hread(HB, wsw, 160 + hi16),
                      g6 = hread(HB, wsw, 192 + hi16), g7 = hread(HB, wsw, 224 + hi16);
                { f32x16 a = bias_init(LB2);       a = mm8(LW2, (0<<13)+colr2, swb2, g0,g1,g2,g3,g4,g5,g6,g7, a); store_tile(HB, wsw,   0, hi8, a); }
                { f32x16 a = bias_init(LB2 + 128); a = mm8(LW2, (1<<13)+colr2, swb2, g0,g1,g2,g3,g4,g5,g6,g7, a); store_tile(HB, wsw,  64, hi8, a); }
                { f32x16 a = bias_init(LB2 + 256); a = mm8(LW2, (2<<13)+colr2, swb2, g0,g1,g2,g3,g4,g5,g6,g7, a); store_tile(HB, wsw, 128, hi8, a); }
                { f32x16 a = bias_init(LB2 + 384); a = mm8(LW2, (3<<13)+colr2, swb2, g0,g1,g2,g3,g4,g5,g6,g7, a); store_tile(HB, wsw, 192, hi8, a); }
            }

            // ---- layer 3 + fused layer-4 dot (no H write) ----
            float p = 0.0f;
            {
                half8 g0 = hread(HB, wsw,   0 + hi16), g1 = hread(HB, wsw,  32 + hi16),
                      g2 = hread(HB, wsw,  64 + hi16), g3 = hread(HB, wsw,  96 + hi16),
                      g4 = hread(HB, wsw, 128 + hi16), g5 = hread(HB, wsw, 160 + hi16),
                      g6 = hread(HB, wsw, 192 + hi16), g7 = hread(HB, wsw, 224 + hi16);
#define L3TILE(IT) { \
                f32x16 a = bias_init(LB3 + (IT)*128); \
                a = mm8(LW3, ((IT)<<13)+colr2, swb2, g0,g1,g2,g3,g4,g5,g6,g7, a); \
                float4 w0 = *(const float4*)(LV4 + (IT)*128); \
                float4 w1 = *(const float4*)(LV4 + (IT)*128 + 32); \
                float4 w2 = *(const float4*)(LV4 + (IT)*128 + 64); \
                float4 w3 = *(const float4*)(LV4 + (IT)*128 + 96); \
                p += fast_tanh(a[0])*w0.x  + fast_tanh(a[1])*w0.y  + fast_tanh(a[2])*w0.z  + fast_tanh(a[3])*w0.w \
                   + fast_tanh(a[4])*w1.x  + fast_tanh(a[5])*w1.y  + fast_tanh(a[6])*w1.z  + fast_tanh(a[7])*w1.w \
                   + fast_tanh(a[8])*w2.x  + fast_tanh(a[9])*w2.y  + fast_tanh(a[10])*w2.z + fast_tanh(a[11])*w2.w \
                   + fast_tanh(a[12])*w3.x + fast_tanh(a[13])*w3.y + fast_tanh(a[14])*w3.z + fast_tanh(a[15])*w3.w; }
                L3TILE(0); L3TILE(1); L3TILE(2); L3TILE(3);
#undef L3TILE
            }

            // full h-sum for edge `col` lives in lanes col and col+32
            p += __shfl_xor(p, 32, 64);
            if (lane < 32) out[ebase + col] = fast_sigmoid(p + bb);
        }
    }
}

extern "C" void kernel_launch(void* const* d_in, const int* in_sizes, int n_in,
                              void* d_out, int out_size, void* d_ws, size_t ws_size,
                              hipStream_t stream) {
    // setup_inputs order: x, edge_index, edge_attr, W1,b1, W2,b2, W3,b3, W4,b4
    const float* ea = (const float*)d_in[2];
    const float* W1 = (const float*)d_in[3];
    const float* b1 = (const float*)d_in[4];
    const float* W2 = (const float*)d_in[5];
    const float* b2 = (const float*)d_in[6];
    const float* W3 = (const float*)d_in[7];
    const float* b3 = (const float*)d_in[8];
    const float* W4 = (const float*)d_in[9];
    const float* b4 = (const float*)d_in[10];
    float* out = (float*)d_out;

    hipLaunchKernelGGL(gnn_mlp, dim3(GRID), dim3(TPB), 0, stream,
                       ea, W1, b1, W2, b2, W3, b3, W4, b4, out);
}